// Round 11
// baseline (254.571 us; speedup 1.0000x reference)
//
#include <hip/hip_runtime.h>
#include <math.h>

#define DCH 256      // d_model
#define BSZ 512      // graphs
#define NPG 200      // nodes per graph
#define G4  1024     // 4*D
#define K2  512      // 2*D

typedef __attribute__((ext_vector_type(8))) short short8v;  // 8 bf16
typedef __attribute__((ext_vector_type(4))) float f32x4;

__device__ __forceinline__ float sigf(float x) { return 1.0f / (1.0f + __expf(-x)); }

// ---- bf16 pack/unpack (RNE) ----
__device__ __forceinline__ unsigned pack2bf(float a, float b) {
    unsigned ua = __float_as_uint(a), ub = __float_as_uint(b);
    ua = (ua + 0x7FFFu + ((ua >> 16) & 1u)) >> 16;
    ub = (ub + 0x7FFFu + ((ub >> 16) & 1u)) & 0xFFFF0000u;
    return ua | ub;           // a -> low16, b -> high16
}
__device__ __forceinline__ float lo_bf(unsigned u) { return __uint_as_float(u << 16); }
__device__ __forceinline__ float hi_bf(unsigned u) { return __uint_as_float(u & 0xFFFF0000u); }

// ---------------------------------------------------------------------------
// prep: Wcat[n][k] = bf16(W_ih[n,k] + (k<256 ? W_hh[n,k] : 0))  [1024x512]
//       WoBf[n][k] = bf16(Wo[n,k])                              [256x512]
// ---------------------------------------------------------------------------
__global__ __launch_bounds__(256) void prep_kernel(
    const float* __restrict__ W_ih, const float* __restrict__ W_hh,
    const float* __restrict__ Wo,
    uint4* __restrict__ wcat, uint4* __restrict__ wobf)
{
    int idx = blockIdx.x * 256 + threadIdx.x;
    if (idx < 65536) {
        const int n = idx >> 6, k = (idx & 63) * 8;
        float v[8];
        *(float4*)(v)     = *(const float4*)(W_ih + (size_t)n * K2 + k);
        *(float4*)(v + 4) = *(const float4*)(W_ih + (size_t)n * K2 + k + 4);
        if (k < DCH) {
            float h[8];
            *(float4*)(h)     = *(const float4*)(W_hh + (size_t)n * DCH + k);
            *(float4*)(h + 4) = *(const float4*)(W_hh + (size_t)n * DCH + k + 4);
            #pragma unroll
            for (int i = 0; i < 8; ++i) v[i] += h[i];
        }
        uint4 u;
        u.x = pack2bf(v[0], v[1]); u.y = pack2bf(v[2], v[3]);
        u.z = pack2bf(v[4], v[5]); u.w = pack2bf(v[6], v[7]);
        wcat[idx] = u;
    } else {
        idx -= 65536;
        const int n = idx >> 6, k = (idx & 63) * 8;
        float v[8];
        *(float4*)(v)     = *(const float4*)(Wo + (size_t)n * K2 + k);
        *(float4*)(v + 4) = *(const float4*)(Wo + (size_t)n * K2 + k + 4);
        uint4 u;
        u.x = pack2bf(v[0], v[1]); u.y = pack2bf(v[2], v[3]);
        u.z = pack2bf(v[4], v[5]); u.w = pack2bf(v[6], v[7]);
        wobf[idx] = u;
    }
}

// ---------------------------------------------------------------------------
// Mono kernel: all 4 steps per block. 256 blocks x 512 threads; each
// 256-thread half owns one graph (b = blockIdx.x*2 + half). No cross-block
// dependency exists (gates[b] needs only q_star[b]), so no grid sync.
// Per step: [s>0: MFMA GEMV gates (all 8 waves, graphs = D cols 0,1)] ->
// LSTM (c in register) -> online-softmax attention per half (pass 1 builds
// bf16 node cache; passes 2-4 read it) -> pack q_star bf16 to LDS | out-proj.
// LDS: smem2[2][4640] attn working | gatesLDS[2][1024] | qsbf[2][256] u32.
// ---------------------------------------------------------------------------
__global__ void __launch_bounds__(512, 1) mono_kernel(
    const float* __restrict__ node, const int* __restrict__ node_num,
    const float* __restrict__ b_ih, const float* __restrict__ b_hh,
    const unsigned short* __restrict__ wcat, const uint4* __restrict__ wobf,
    const float* __restrict__ bo,
    uint4* __restrict__ nbf, float* __restrict__ outp)
{
    __shared__ __align__(16) float smem2[2][4640];
    __shared__ __align__(16) float gatesLDS[2][1024];
    __shared__ __align__(16) unsigned qsbf[2][256];

    const int tid = threadIdx.x;
    const int half = tid >> 8, t = tid & 255;
    const int b = blockIdx.x * 2 + half;

    float* smem = smem2[half];
    float* qs = smem;                                  // [512]: h | r
    float (*red_r)[DCH] = (float (*)[DCH])(smem + 512);
    float* red_m = smem + 4608;
    float* red_s = smem + 4624;

    // attention lane geometry (within half)
    const int w = t >> 6, l = t & 63;
    const int p = l & 15;
    const int g = w * 4 + (l >> 4);
    const int cnt = node_num[b];
    const float* nb = node + (size_t)b * NPG * DCH;
    uint4* nbf_b = nbf + (size_t)b * NPG * 32;         // 32 uint4 per node

    // GEMV lane geometry (block-wide)
    const int wv = tid >> 6;                           // wave 0..7
    const int lane = tid & 63;
    const int rsel = lane & 15, kgrp = lane >> 4;

    // biases cached in registers
    float bsum_r[4];
    #pragma unroll
    for (int q = 0; q < 4; ++q) bsum_r[q] = b_ih[q * DCH + t] + b_hh[q * DCH + t];

    float c_reg = 0.0f;

    for (int s = 0; s < 4; ++s) {
        // ---- GEMV: gatesLDS[2][1024] = q_star(bf16) @ Wcat^T ----
        if (s > 0) {
            f32x4 acc[8] = {};
            const unsigned short* qrow = (const unsigned short*)qsbf[rsel & 1];
            for (int ks = 0; ks < 16; ++ks) {
                const int kk = ks * 32 + kgrp * 8;
                const short8v qb = *(const short8v*)(qrow + kk);
                #pragma unroll
                for (int j = 0; j < 8; ++j) {
                    const int grow = (wv * 8 + j) * 16 + rsel;
                    const short8v wa = *(const short8v*)(wcat + (size_t)grow * K2 + kk);
                    acc[j] = __builtin_amdgcn_mfma_f32_16x16x32_bf16(wa, qb, acc[j], 0, 0, 0);
                }
            }
            // D: row = gate = kgrp*4 + reg (A side), col = graph = rsel (B side)
            if (rsel < 2) {
                #pragma unroll
                for (int j = 0; j < 8; ++j)
                    *(f32x4*)(&gatesLDS[rsel][(wv * 8 + j) * 16 + kgrp * 4]) = acc[j];
            }
        }
        __syncthreads();   // gates ready (uniform: s is block-uniform)

        // ---- LSTM cell (torch gate order i,f,g,o) ----
        float gv[4];
        #pragma unroll
        for (int q = 0; q < 4; ++q) {
            float v = bsum_r[q];
            if (s > 0) v += gatesLDS[half][q * DCH + t];
            gv[q] = v;
        }
        const float cn = sigf(gv[1]) * c_reg + sigf(gv[0]) * tanhf(gv[2]);
        const float hn = sigf(gv[3]) * tanhf(cn);
        c_reg = cn;
        qs[t] = hn;
        __syncthreads();

        // ---- attention: 16-lane clusters, depth-2 prefetch ----
        const bool first = (s == 0);
        float4 qv[4];
        #pragma unroll
        for (int j = 0; j < 2; ++j) {
            qv[j*2+0] = *(const float4*)(qs + j * 128 + p * 8);
            qv[j*2+1] = *(const float4*)(qs + j * 128 + p * 8 + 4);
        }

        auto ld = [&](int n, float4* x) {
            if (n < cnt) {
                if (first) {
                    #pragma unroll
                    for (int j = 0; j < 2; ++j) {
                        x[j*2+0] = *(const float4*)(nb + (size_t)n * DCH + j * 128 + p * 8);
                        x[j*2+1] = *(const float4*)(nb + (size_t)n * DCH + j * 128 + p * 8 + 4);
                    }
                } else {
                    #pragma unroll
                    for (int j = 0; j < 2; ++j) {
                        const uint4 u = nbf_b[(size_t)n * 32 + j * 16 + p];
                        x[j*2+0] = make_float4(lo_bf(u.x), hi_bf(u.x), lo_bf(u.y), hi_bf(u.y));
                        x[j*2+1] = make_float4(lo_bf(u.z), hi_bf(u.z), lo_bf(u.w), hi_bf(u.w));
                    }
                }
            } else {
                x[0] = x[1] = x[2] = x[3] = make_float4(0.f, 0.f, 0.f, 0.f);
            }
        };
        auto st_bf = [&](int n, const float4* x) {
            if (n < cnt) {
                #pragma unroll
                for (int j = 0; j < 2; ++j) {
                    uint4 u;
                    u.x = pack2bf(x[j*2+0].x, x[j*2+0].y);
                    u.y = pack2bf(x[j*2+0].z, x[j*2+0].w);
                    u.z = pack2bf(x[j*2+1].x, x[j*2+1].y);
                    u.w = pack2bf(x[j*2+1].z, x[j*2+1].w);
                    nbf_b[(size_t)n * 32 + j * 16 + p] = u;
                }
            }
        };

        float m = -INFINITY, ssum = 0.0f;
        float4 racc[4] = {};
        const int nit = (cnt + 31) >> 5;

        float4 x0[4], x1[4], u0[4], u1[4];
        ld(2 * g, x0);      ld(2 * g + 1, x1);
        ld(32 + 2 * g, u0); ld(32 + 2 * g + 1, u1);

        for (int it = 0; it < nit; ++it) {              // no barriers inside
            const int n0 = it * 32 + 2 * g;
            float4 y0[4], y1[4];
            ld(n0 + 64, y0); ld(n0 + 65, y1);
            if (first) { st_bf(n0, x0); st_bf(n0 + 1, x1); }

            float e0 = 0.f, e1 = 0.f;
            #pragma unroll
            for (int j = 0; j < 4; ++j) {
                e0 += x0[j].x * qv[j].x + x0[j].y * qv[j].y + x0[j].z * qv[j].z + x0[j].w * qv[j].w;
                e1 += x1[j].x * qv[j].x + x1[j].y * qv[j].y + x1[j].z * qv[j].z + x1[j].w * qv[j].w;
            }
            #pragma unroll
            for (int off = 1; off < 16; off <<= 1) {
                e0 += __shfl_xor(e0, off);
                e1 += __shfl_xor(e1, off);
            }
            if (n0     >= cnt) e0 = -INFINITY;
            if (n0 + 1 >= cnt) e1 = -INFINITY;
            const float mn = fmaxf(m, fmaxf(e0, e1));
            if (mn > -INFINITY) {
                const float sc = __expf(m - mn);
                const float w0 = __expf(e0 - mn);
                const float w1 = __expf(e1 - mn);
                ssum = ssum * sc + w0 + w1;
                #pragma unroll
                for (int j = 0; j < 4; ++j) {
                    racc[j].x = racc[j].x * sc + w0 * x0[j].x + w1 * x1[j].x;
                    racc[j].y = racc[j].y * sc + w0 * x0[j].y + w1 * x1[j].y;
                    racc[j].z = racc[j].z * sc + w0 * x0[j].z + w1 * x1[j].z;
                    racc[j].w = racc[j].w * sc + w0 * x0[j].w + w1 * x1[j].w;
                }
                m = mn;
            }
            #pragma unroll
            for (int j = 0; j < 4; ++j) {
                x0[j] = u0[j]; x1[j] = u1[j];
                u0[j] = y0[j]; u1[j] = y1[j];
            }
        }

        #pragma unroll
        for (int j = 0; j < 2; ++j) {
            *(float4*)(&red_r[g][j * 128 + p * 8])     = racc[j*2+0];
            *(float4*)(&red_r[g][j * 128 + p * 8 + 4]) = racc[j*2+1];
        }
        if (p == 0) { red_m[g] = m; red_s[g] = ssum; }
        __syncthreads();

        float M = -INFINITY;
        #pragma unroll
        for (int g2 = 0; g2 < 16; ++g2) M = fmaxf(M, red_m[g2]);
        float stot = 0.0f, rtot = 0.0f;
        #pragma unroll
        for (int g2 = 0; g2 < 16; ++g2) {
            const float sc = __expf(red_m[g2] - M);
            stot += sc * red_s[g2];
            rtot += sc * red_r[g2][t];
        }
        rtot = rtot / (stot + 1e-6f);

        qs[256 + t] = rtot;            // q_star = [h | r]
        __syncthreads();

        if (s < 3) {
            // pack q_star to bf16 LDS for next step's GEMV
            qsbf[half][t] = pack2bf(qs[2 * t], qs[2 * t + 1]);
            __syncthreads();           // qsbf ready before next GEMV
        } else {
            // ---- fused output projection (Wo bf16) ----
            float4 qv2[8];
            #pragma unroll
            for (int j = 0; j < 4; ++j) {
                qv2[j*2+0] = *(const float4*)(qs + j * 128 + p * 8);
                qv2[j*2+1] = *(const float4*)(qs + j * 128 + p * 8 + 4);
            }
            float* out_sm = smem + 512;    // reuse red_r (post-barrier)

            #pragma unroll 2
            for (int v = 0; v < 8; ++v) {
                const int o0 = (2 * v) * 16 + g;
                const int o1 = o0 + 16;
                float e0 = 0.f, e1 = 0.f;
                #pragma unroll
                for (int j = 0; j < 4; ++j) {
                    const uint4 ua = wobf[(size_t)o0 * 64 + j * 16 + p];
                    const uint4 ub = wobf[(size_t)o1 * 64 + j * 16 + p];
                    e0 += lo_bf(ua.x) * qv2[j*2].x + hi_bf(ua.x) * qv2[j*2].y
                        + lo_bf(ua.y) * qv2[j*2].z + hi_bf(ua.y) * qv2[j*2].w
                        + lo_bf(ua.z) * qv2[j*2+1].x + hi_bf(ua.z) * qv2[j*2+1].y
                        + lo_bf(ua.w) * qv2[j*2+1].z + hi_bf(ua.w) * qv2[j*2+1].w;
                    e1 += lo_bf(ub.x) * qv2[j*2].x + hi_bf(ub.x) * qv2[j*2].y
                        + lo_bf(ub.y) * qv2[j*2].z + hi_bf(ub.y) * qv2[j*2].w
                        + lo_bf(ub.z) * qv2[j*2+1].x + hi_bf(ub.z) * qv2[j*2+1].y
                        + lo_bf(ub.w) * qv2[j*2+1].z + hi_bf(ub.w) * qv2[j*2+1].w;
                }
                #pragma unroll
                for (int off = 1; off < 16; off <<= 1) {
                    e0 += __shfl_xor(e0, off);
                    e1 += __shfl_xor(e1, off);
                }
                if (p == 0) {
                    out_sm[o0] = e0 + bo[o0];
                    out_sm[o1] = e1 + bo[o1];
                }
            }
            __syncthreads();
            outp[(size_t)b * DCH + t] = out_sm[t];
        }
    }
}

// ---------------------------------------------------------------------------
extern "C" void kernel_launch(void* const* d_in, const int* in_sizes, int n_in,
                              void* d_out, int out_size, void* d_ws, size_t ws_size,
                              hipStream_t stream)
{
    const float* node     = (const float*)d_in[0];
    const int*   node_num = (const int*)  d_in[1];
    const float* W_ih     = (const float*)d_in[2];
    const float* W_hh     = (const float*)d_in[3];
    const float* b_ih     = (const float*)d_in[4];
    const float* b_hh     = (const float*)d_in[5];
    const float* Wo       = (const float*)d_in[6];
    const float* bo       = (const float*)d_in[7];
    float* out = (float*)d_out;

    uint4* wcat = (uint4*)d_ws;                 // 1024*64 uint4 (1 MB)
    uint4* wobf = wcat + 1024 * 64;             // 256*64 uint4 (256 KB)
    uint4* nbf  = wobf + 256 * 64;              // bf16 node cache (52.4 MB)

    prep_kernel<<<320, 256, 0, stream>>>(W_ih, W_hh, Wo, wcat, wobf);

    mono_kernel<<<BSZ / 2, 512, 0, stream>>>(
        node, node_num, b_ih, b_hh,
        (const unsigned short*)wcat, wobf, bo, nbf, out);
}

// Round 12
// 118.772 us; speedup vs baseline: 2.1434x; 2.1434x over previous
//
#include <hip/hip_runtime.h>
#include <math.h>

#define DCH 256      // d_model
#define BSZ 512      // graphs
#define NPG 200      // nodes per graph
#define G4  1024     // 4*D
#define K2  512      // 2*D
#define KSD 4        // k-split for gates GEMM (grid 8x8x4 = 256 blocks)

typedef __attribute__((ext_vector_type(8))) short short8v;  // 8 bf16
typedef __attribute__((ext_vector_type(4))) float f32x4;

__device__ __forceinline__ float sigf(float x) { return 1.0f / (1.0f + __expf(-x)); }

// ---- bf16 pack/unpack (RNE) ----
__device__ __forceinline__ unsigned pack2bf(float a, float b) {
    unsigned ua = __float_as_uint(a), ub = __float_as_uint(b);
    ua = (ua + 0x7FFFu + ((ua >> 16) & 1u)) >> 16;
    ub = (ub + 0x7FFFu + ((ub >> 16) & 1u)) & 0xFFFF0000u;
    return ua | ub;           // a -> low16, b -> high16
}
__device__ __forceinline__ float lo_bf(unsigned u) { return __uint_as_float(u << 16); }
__device__ __forceinline__ float hi_bf(unsigned u) { return __uint_as_float(u & 0xFFFF0000u); }

// ---------------------------------------------------------------------------
// MFMA gates GEMM partial (round-10 proven, operands swapped):
// gpart[z][m][n] = sum_{k in slice z} qstar_bf[m,k] * Wcat[n,k]
// D: row = gate (A side) = (lane>>4)*4 + reg, col = graph (B side) = lane&15
// -> each lane stores 8 float4 contiguous in the gate dim.
// ---------------------------------------------------------------------------
__global__ __launch_bounds__(256) void gemm_gates_mfma(
    const unsigned short* __restrict__ hrbf,   // [BSZ][512] bf16 q_star
    const unsigned short* __restrict__ wcat,   // [1024][512] bf16
    float* __restrict__ gpart, int Kper)
{
    const int wid  = threadIdx.x >> 6;
    const int lane = threadIdx.x & 63;
    const int gx = blockIdx.x * 128 + wid * 32;   // gate base (A side)
    const int gm = blockIdx.y * 64;               // graph base (B side)
    const int kbase = blockIdx.z * Kper;
    const int rsel = lane & 15, kgrp = lane >> 4;

    f32x4 a0m0 = {}, a0m1 = {}, a0m2 = {}, a0m3 = {},
          a1m0 = {}, a1m1 = {}, a1m2 = {}, a1m3 = {};

    for (int k0 = 0; k0 < Kper; k0 += 32) {
        const int kk = kbase + k0 + kgrp * 8;
        short8v wa0 = *(const short8v*)(wcat + (size_t)(gx +  0 + rsel) * K2 + kk);
        short8v wa1 = *(const short8v*)(wcat + (size_t)(gx + 16 + rsel) * K2 + kk);
        short8v qb0 = *(const short8v*)(hrbf + (size_t)(gm +  0 + rsel) * K2 + kk);
        short8v qb1 = *(const short8v*)(hrbf + (size_t)(gm + 16 + rsel) * K2 + kk);
        short8v qb2 = *(const short8v*)(hrbf + (size_t)(gm + 32 + rsel) * K2 + kk);
        short8v qb3 = *(const short8v*)(hrbf + (size_t)(gm + 48 + rsel) * K2 + kk);
        a0m0 = __builtin_amdgcn_mfma_f32_16x16x32_bf16(wa0, qb0, a0m0, 0, 0, 0);
        a0m1 = __builtin_amdgcn_mfma_f32_16x16x32_bf16(wa0, qb1, a0m1, 0, 0, 0);
        a0m2 = __builtin_amdgcn_mfma_f32_16x16x32_bf16(wa0, qb2, a0m2, 0, 0, 0);
        a0m3 = __builtin_amdgcn_mfma_f32_16x16x32_bf16(wa0, qb3, a0m3, 0, 0, 0);
        a1m0 = __builtin_amdgcn_mfma_f32_16x16x32_bf16(wa1, qb0, a1m0, 0, 0, 0);
        a1m1 = __builtin_amdgcn_mfma_f32_16x16x32_bf16(wa1, qb1, a1m1, 0, 0, 0);
        a1m2 = __builtin_amdgcn_mfma_f32_16x16x32_bf16(wa1, qb2, a1m2, 0, 0, 0);
        a1m3 = __builtin_amdgcn_mfma_f32_16x16x32_bf16(wa1, qb3, a1m3, 0, 0, 0);
    }

    float* Cp = gpart + (size_t)blockIdx.z * BSZ * G4;
    const int gr = kgrp * 4;
    #define STORE_ACC(ni, mi, accv) \
        *(f32x4*)(Cp + (size_t)(gm + (mi)*16 + rsel) * G4 + gx + (ni)*16 + gr) = (accv);
    STORE_ACC(0, 0, a0m0) STORE_ACC(0, 1, a0m1) STORE_ACC(0, 2, a0m2) STORE_ACC(0, 3, a0m3)
    STORE_ACC(1, 0, a1m0) STORE_ACC(1, 1, a1m1) STORE_ACC(1, 2, a1m2) STORE_ACC(1, 3, a1m3)
    #undef STORE_ACC
}

// ---------------------------------------------------------------------------
// Fused LSTM + online-softmax attention (+ out-proj if LAST; + weight convert
// if FIRST). NOW 512 threads per graph block (16 waves/CU vs 8) to attack the
// latency-bound regime mono's counters exposed. 32 clusters x 16 lanes;
// cluster g handles nodes {it*64 + 2g, +1}; depth-2 prefetch.
// smem: qs[512] | red_r[32][256] @512 | red_m[32] @8704 | red_s[32] @8736
// ---------------------------------------------------------------------------
template<int FIRST, int LAST>
__global__ __launch_bounds__(512) void lstm_attn_kernel(
    const float* __restrict__ gpart,
    const float* __restrict__ b_ih, const float* __restrict__ b_hh,
    const float* __restrict__ node, uint4* __restrict__ nbf,
    const int* __restrict__ node_num,
    float* __restrict__ cbuf, unsigned* __restrict__ hrbf,
    const float* __restrict__ W_ih, const float* __restrict__ W_hh,
    const float* __restrict__ Wo,
    uint4* __restrict__ wcat, uint4* __restrict__ wobf,
    const float* __restrict__ bo, float* __restrict__ outp)
{
    __shared__ __align__(16) float smem[8768];
    float* qs = smem;                                  // [512]: h | r
    float (*red_r)[DCH] = (float (*)[DCH])(smem + 512);
    float* red_m = smem + 8704;
    float* red_s = smem + 8736;

    const int b = blockIdx.x;
    const int t = threadIdx.x;                         // 0..511

    // ---- fused weight conversion (FIRST only): 160 chunks per block ----
    if (FIRST) {
        if (t < 160) {
            int idx = blockIdx.x * 160 + t;            // 0..81919
            if (idx < 65536) {                         // Wcat chunk
                const int n = idx >> 6, k = (idx & 63) * 8;
                float v[8];
                *(float4*)(v)     = *(const float4*)(W_ih + (size_t)n * K2 + k);
                *(float4*)(v + 4) = *(const float4*)(W_ih + (size_t)n * K2 + k + 4);
                if (k < DCH) {
                    float h[8];
                    *(float4*)(h)     = *(const float4*)(W_hh + (size_t)n * DCH + k);
                    *(float4*)(h + 4) = *(const float4*)(W_hh + (size_t)n * DCH + k + 4);
                    #pragma unroll
                    for (int i = 0; i < 8; ++i) v[i] += h[i];
                }
                uint4 u;
                u.x = pack2bf(v[0], v[1]); u.y = pack2bf(v[2], v[3]);
                u.z = pack2bf(v[4], v[5]); u.w = pack2bf(v[6], v[7]);
                wcat[idx] = u;
            } else {                                   // WoBf chunk
                const int i2 = idx - 65536;
                const int n = i2 >> 6, k = (i2 & 63) * 8;
                float v[8];
                *(float4*)(v)     = *(const float4*)(Wo + (size_t)n * K2 + k);
                *(float4*)(v + 4) = *(const float4*)(Wo + (size_t)n * K2 + k + 4);
                uint4 u;
                u.x = pack2bf(v[0], v[1]); u.y = pack2bf(v[2], v[3]);
                u.z = pack2bf(v[4], v[5]); u.w = pack2bf(v[6], v[7]);
                wobf[i2] = u;
            }
        }
    }

    // ---- LSTM cell (torch gate order i,f,g,o) — threads t<256 ----
    if (t < DCH) {
        float gv[4];
        #pragma unroll
        for (int q = 0; q < 4; ++q) {
            const int idx = q * DCH + t;
            float v = b_ih[idx] + b_hh[idx];
            if (!FIRST) {
                #pragma unroll
                for (int z = 0; z < KSD; ++z)
                    v += gpart[(size_t)z * BSZ * G4 + (size_t)b * G4 + idx];
            }
            gv[q] = v;
        }
        const float c_old = FIRST ? 0.0f : cbuf[b * DCH + t];
        const float cn = sigf(gv[1]) * c_old + sigf(gv[0]) * tanhf(gv[2]);
        const float hn = sigf(gv[3]) * tanhf(cn);
        if (!LAST) cbuf[b * DCH + t] = cn;
        qs[t] = hn;
    }
    __syncthreads();

    // ---- attention: 32 clusters of 16 lanes, depth-2 prefetch ----
    const int l = t & 63;
    const int p = l & 15;
    const int g = (t >> 6) * 4 + (l >> 4);       // cluster 0..31
    const int cnt = node_num[b];
    const float* nb = node + (size_t)b * NPG * DCH;
    uint4* nbf_b = nbf + (size_t)b * NPG * 32;   // 32 uint4 per node

    float4 qv[4];
    #pragma unroll
    for (int j = 0; j < 2; ++j) {
        qv[j*2+0] = *(const float4*)(qs + j * 128 + p * 8);
        qv[j*2+1] = *(const float4*)(qs + j * 128 + p * 8 + 4);
    }

    auto ld = [&](int n, float4* x) {
        if (n < cnt) {
            if (FIRST) {
                #pragma unroll
                for (int j = 0; j < 2; ++j) {
                    x[j*2+0] = *(const float4*)(nb + (size_t)n * DCH + j * 128 + p * 8);
                    x[j*2+1] = *(const float4*)(nb + (size_t)n * DCH + j * 128 + p * 8 + 4);
                }
            } else {
                #pragma unroll
                for (int j = 0; j < 2; ++j) {
                    const uint4 u = nbf_b[(size_t)n * 32 + j * 16 + p];
                    x[j*2+0] = make_float4(lo_bf(u.x), hi_bf(u.x), lo_bf(u.y), hi_bf(u.y));
                    x[j*2+1] = make_float4(lo_bf(u.z), hi_bf(u.z), lo_bf(u.w), hi_bf(u.w));
                }
            }
        } else {
            x[0] = x[1] = x[2] = x[3] = make_float4(0.f, 0.f, 0.f, 0.f);
        }
    };
    auto st_bf = [&](int n, const float4* x) {
        if (n < cnt) {
            #pragma unroll
            for (int j = 0; j < 2; ++j) {
                uint4 u;
                u.x = pack2bf(x[j*2+0].x, x[j*2+0].y);
                u.y = pack2bf(x[j*2+0].z, x[j*2+0].w);
                u.z = pack2bf(x[j*2+1].x, x[j*2+1].y);
                u.w = pack2bf(x[j*2+1].z, x[j*2+1].w);
                nbf_b[(size_t)n * 32 + j * 16 + p] = u;
            }
        }
    };

    float m = -INFINITY, ssum = 0.0f;
    float4 racc[4] = {};
    const int nit = (cnt + 63) >> 6;

    float4 x0[4], x1[4], u0[4], u1[4];
    ld(2 * g, x0);      ld(2 * g + 1, x1);
    ld(64 + 2 * g, u0); ld(64 + 2 * g + 1, u1);

    for (int it = 0; it < nit; ++it) {           // no barriers inside
        const int n0 = it * 64 + 2 * g;
        float4 y0[4], y1[4];
        ld(n0 + 128, y0); ld(n0 + 129, y1);
        if (FIRST) { st_bf(n0, x0); st_bf(n0 + 1, x1); }

        float e0 = 0.f, e1 = 0.f;
        #pragma unroll
        for (int j = 0; j < 4; ++j) {
            e0 += x0[j].x * qv[j].x + x0[j].y * qv[j].y + x0[j].z * qv[j].z + x0[j].w * qv[j].w;
            e1 += x1[j].x * qv[j].x + x1[j].y * qv[j].y + x1[j].z * qv[j].z + x1[j].w * qv[j].w;
        }
        #pragma unroll
        for (int off = 1; off < 16; off <<= 1) {
            e0 += __shfl_xor(e0, off);
            e1 += __shfl_xor(e1, off);
        }
        if (n0     >= cnt) e0 = -INFINITY;
        if (n0 + 1 >= cnt) e1 = -INFINITY;
        const float mn = fmaxf(m, fmaxf(e0, e1));
        if (mn > -INFINITY) {
            const float sc = __expf(m - mn);
            const float w0 = __expf(e0 - mn);
            const float w1 = __expf(e1 - mn);
            ssum = ssum * sc + w0 + w1;
            #pragma unroll
            for (int j = 0; j < 4; ++j) {
                racc[j].x = racc[j].x * sc + w0 * x0[j].x + w1 * x1[j].x;
                racc[j].y = racc[j].y * sc + w0 * x0[j].y + w1 * x1[j].y;
                racc[j].z = racc[j].z * sc + w0 * x0[j].z + w1 * x1[j].z;
                racc[j].w = racc[j].w * sc + w0 * x0[j].w + w1 * x1[j].w;
            }
            m = mn;
        }
        #pragma unroll
        for (int j = 0; j < 4; ++j) {
            x0[j] = u0[j]; x1[j] = u1[j];
            u0[j] = y0[j]; u1[j] = y1[j];
        }
    }

    #pragma unroll
    for (int j = 0; j < 2; ++j) {
        *(float4*)(&red_r[g][j * 128 + p * 8])     = racc[j*2+0];
        *(float4*)(&red_r[g][j * 128 + p * 8 + 4]) = racc[j*2+1];
    }
    if (p == 0) { red_m[g] = m; red_s[g] = ssum; }
    __syncthreads();

    float rtot = 0.0f;
    if (t < DCH) {
        float M = -INFINITY;
        #pragma unroll
        for (int g2 = 0; g2 < 32; ++g2) M = fmaxf(M, red_m[g2]);
        float stot = 0.0f;
        #pragma unroll
        for (int g2 = 0; g2 < 32; ++g2) {
            const float sc = __expf(red_m[g2] - M);
            stot += sc * red_s[g2];
            rtot += sc * red_r[g2][t];
        }
        rtot = rtot / (stot + 1e-6f);
    }
    __syncthreads();                 // red_r reads done before qs[256+] write
    if (t < DCH) qs[256 + t] = rtot; // q_star = [h | r]
    __syncthreads();

    if (!LAST) {
        if (t < DCH)
            hrbf[b * 256 + t] = pack2bf(qs[2 * t], qs[2 * t + 1]);
        return;
    }

    // ---- fused output projection (Wo bf16), 32 clusters x 4 iters ----
    float4 qv2[8];
    #pragma unroll
    for (int j = 0; j < 4; ++j) {
        qv2[j*2+0] = *(const float4*)(qs + j * 128 + p * 8);
        qv2[j*2+1] = *(const float4*)(qs + j * 128 + p * 8 + 4);
    }
    float* out_sm = smem + 512;      // reuse red_r area (post-barrier)

    #pragma unroll 2
    for (int v = 0; v < 4; ++v) {
        const int o0 = (2 * v) * 32 + g;
        const int o1 = o0 + 32;
        float e0 = 0.f, e1 = 0.f;
        #pragma unroll
        for (int j = 0; j < 4; ++j) {
            const uint4 ua = wobf[(size_t)o0 * 64 + j * 16 + p];
            const uint4 ub = wobf[(size_t)o1 * 64 + j * 16 + p];
            e0 += lo_bf(ua.x) * qv2[j*2].x + hi_bf(ua.x) * qv2[j*2].y
                + lo_bf(ua.y) * qv2[j*2].z + hi_bf(ua.y) * qv2[j*2].w
                + lo_bf(ua.z) * qv2[j*2+1].x + hi_bf(ua.z) * qv2[j*2+1].y
                + lo_bf(ua.w) * qv2[j*2+1].z + hi_bf(ua.w) * qv2[j*2+1].w;
            e1 += lo_bf(ub.x) * qv2[j*2].x + hi_bf(ub.x) * qv2[j*2].y
                + lo_bf(ub.y) * qv2[j*2].z + hi_bf(ub.y) * qv2[j*2].w
                + lo_bf(ub.z) * qv2[j*2+1].x + hi_bf(ub.z) * qv2[j*2+1].y
                + lo_bf(ub.w) * qv2[j*2+1].z + hi_bf(ub.w) * qv2[j*2+1].w;
        }
        #pragma unroll
        for (int off = 1; off < 16; off <<= 1) {
            e0 += __shfl_xor(e0, off);
            e1 += __shfl_xor(e1, off);
        }
        if (p == 0) {
            out_sm[o0] = e0 + bo[o0];
            out_sm[o1] = e1 + bo[o1];
        }
    }
    __syncthreads();
    if (t < DCH) outp[(size_t)b * DCH + t] = out_sm[t];
}

// ---------------------------------------------------------------------------
extern "C" void kernel_launch(void* const* d_in, const int* in_sizes, int n_in,
                              void* d_out, int out_size, void* d_ws, size_t ws_size,
                              hipStream_t stream)
{
    const float* node     = (const float*)d_in[0];
    const int*   node_num = (const int*)  d_in[1];
    const float* W_ih     = (const float*)d_in[2];
    const float* W_hh     = (const float*)d_in[3];
    const float* b_ih     = (const float*)d_in[4];
    const float* b_hh     = (const float*)d_in[5];
    const float* Wo       = (const float*)d_in[6];
    const float* bo       = (const float*)d_in[7];
    float* out = (float*)d_out;

    float* ws      = (float*)d_ws;
    float* cbuf    = ws;                                   // 512*256 f32
    unsigned* hrbf = (unsigned*)(cbuf + BSZ * DCH);        // 512*256 u32 (bf16 q_star)
    float* gpart   = (float*)(hrbf + BSZ * 256);           // KSD*512*1024 f32 (8 MB)
    uint4* wcat    = (uint4*)(gpart + (size_t)KSD * BSZ * G4);   // 1 MB
    uint4* wobf    = wcat + 1024 * 64;                     // 256 KB
    uint4* nbf     = wobf + 256 * 64;                      // bf16 node cache (52.4 MB)

    // step 1: gates = biases only; builds bf16 node cache + bf16 weights
    lstm_attn_kernel<1, 0><<<BSZ, 512, 0, stream>>>(
        gpart, b_ih, b_hh, node, nbf, node_num, cbuf, hrbf,
        W_ih, W_hh, Wo, wcat, wobf, bo, out);

    for (int s = 1; s < 4; ++s) {
        gemm_gates_mfma<<<dim3(8, 8, KSD), 256, 0, stream>>>(
            (const unsigned short*)hrbf, (const unsigned short*)wcat, gpart, K2 / KSD);
        if (s < 3) {
            lstm_attn_kernel<0, 0><<<BSZ, 512, 0, stream>>>(
                gpart, b_ih, b_hh, node, nbf, node_num, cbuf, hrbf,
                W_ih, W_hh, Wo, wcat, wobf, bo, out);
        } else {
            lstm_attn_kernel<0, 1><<<BSZ, 512, 0, stream>>>(
                gpart, b_ih, b_hh, node, nbf, node_num, cbuf, hrbf,
                W_ih, W_hh, Wo, wcat, wobf, bo, out);
        }
    }
}

// Round 13
// 105.431 us; speedup vs baseline: 2.4146x; 1.1265x over previous
//
#include <hip/hip_runtime.h>
#include <math.h>

#define DCH 256      // d_model
#define BSZ 512      // graphs
#define NPG 200      // nodes per graph
#define G4  1024     // 4*D
#define K2  512      // 2*D
#define KSD 4        // k-split for gates GEMM (grid 8x8x4 = 256 blocks)
#define NSL 4        // pass-1 slices per graph
#define SLN 50       // nodes per slice

typedef __attribute__((ext_vector_type(8))) short short8v;  // 8 bf16
typedef __attribute__((ext_vector_type(4))) float f32x4;

__device__ __forceinline__ float sigf(float x) { return 1.0f / (1.0f + __expf(-x)); }

// ---- bf16 pack/unpack (RNE) ----
__device__ __forceinline__ unsigned pack2bf(float a, float b) {
    unsigned ua = __float_as_uint(a), ub = __float_as_uint(b);
    ua = (ua + 0x7FFFu + ((ua >> 16) & 1u)) >> 16;
    ub = (ub + 0x7FFFu + ((ub >> 16) & 1u)) & 0xFFFF0000u;
    return ua | ub;           // a -> low16, b -> high16
}
__device__ __forceinline__ float lo_bf(unsigned u) { return __uint_as_float(u << 16); }
__device__ __forceinline__ float hi_bf(unsigned u) { return __uint_as_float(u & 0xFFFF0000u); }

// ---------------------------------------------------------------------------
// MFMA gates GEMM partial (round-10 proven):
// gpart[z][m][n] = sum_{k in slice z} qstar_bf[m,k] * Wcat[n,k]
// D: row = gate (A side) = (lane>>4)*4 + reg, col = graph (B side) = lane&15
// ---------------------------------------------------------------------------
__global__ __launch_bounds__(256) void gemm_gates_mfma(
    const unsigned short* __restrict__ hrbf,   // [BSZ][512] bf16 q_star
    const unsigned short* __restrict__ wcat,   // [1024][512] bf16
    float* __restrict__ gpart, int Kper)
{
    const int wid  = threadIdx.x >> 6;
    const int lane = threadIdx.x & 63;
    const int gx = blockIdx.x * 128 + wid * 32;   // gate base (A side)
    const int gm = blockIdx.y * 64;               // graph base (B side)
    const int kbase = blockIdx.z * Kper;
    const int rsel = lane & 15, kgrp = lane >> 4;

    f32x4 a0m0 = {}, a0m1 = {}, a0m2 = {}, a0m3 = {},
          a1m0 = {}, a1m1 = {}, a1m2 = {}, a1m3 = {};

    for (int k0 = 0; k0 < Kper; k0 += 32) {
        const int kk = kbase + k0 + kgrp * 8;
        short8v wa0 = *(const short8v*)(wcat + (size_t)(gx +  0 + rsel) * K2 + kk);
        short8v wa1 = *(const short8v*)(wcat + (size_t)(gx + 16 + rsel) * K2 + kk);
        short8v qb0 = *(const short8v*)(hrbf + (size_t)(gm +  0 + rsel) * K2 + kk);
        short8v qb1 = *(const short8v*)(hrbf + (size_t)(gm + 16 + rsel) * K2 + kk);
        short8v qb2 = *(const short8v*)(hrbf + (size_t)(gm + 32 + rsel) * K2 + kk);
        short8v qb3 = *(const short8v*)(hrbf + (size_t)(gm + 48 + rsel) * K2 + kk);
        a0m0 = __builtin_amdgcn_mfma_f32_16x16x32_bf16(wa0, qb0, a0m0, 0, 0, 0);
        a0m1 = __builtin_amdgcn_mfma_f32_16x16x32_bf16(wa0, qb1, a0m1, 0, 0, 0);
        a0m2 = __builtin_amdgcn_mfma_f32_16x16x32_bf16(wa0, qb2, a0m2, 0, 0, 0);
        a0m3 = __builtin_amdgcn_mfma_f32_16x16x32_bf16(wa0, qb3, a0m3, 0, 0, 0);
        a1m0 = __builtin_amdgcn_mfma_f32_16x16x32_bf16(wa1, qb0, a1m0, 0, 0, 0);
        a1m1 = __builtin_amdgcn_mfma_f32_16x16x32_bf16(wa1, qb1, a1m1, 0, 0, 0);
        a1m2 = __builtin_amdgcn_mfma_f32_16x16x32_bf16(wa1, qb2, a1m2, 0, 0, 0);
        a1m3 = __builtin_amdgcn_mfma_f32_16x16x32_bf16(wa1, qb3, a1m3, 0, 0, 0);
    }

    float* Cp = gpart + (size_t)blockIdx.z * BSZ * G4;
    const int gr = kgrp * 4;
    #define STORE_ACC(ni, mi, accv) \
        *(f32x4*)(Cp + (size_t)(gm + (mi)*16 + rsel) * G4 + gx + (ni)*16 + gr) = (accv);
    STORE_ACC(0, 0, a0m0) STORE_ACC(0, 1, a0m1) STORE_ACC(0, 2, a0m2) STORE_ACC(0, 3, a0m3)
    STORE_ACC(1, 0, a1m0) STORE_ACC(1, 1, a1m1) STORE_ACC(1, 2, a1m2) STORE_ACC(1, 3, a1m3)
    #undef STORE_ACC
}

// ---------------------------------------------------------------------------
// Pass-1 partial: 4 blocks per graph (bid = b*4+sl). Each block streams its
// 50-node fp32 slice, writes the bf16 node cache for it, and emits RAW
// online-softmax partials (m, s, r[256]) to ws. Also converts 40 weight
// chunks per block (2048*40 = 81920 = exact cover of Wcat+WoBf).
// smem: qs[512] | red_r[16][256] @512 | red_m @4608 | red_s @4624
// ---------------------------------------------------------------------------
__global__ __launch_bounds__(256) void attn1_part_kernel(
    const float* __restrict__ node, const int* __restrict__ node_num,
    const float* __restrict__ b_ih, const float* __restrict__ b_hh,
    const float* __restrict__ W_ih, const float* __restrict__ W_hh,
    const float* __restrict__ Wo,
    uint4* __restrict__ wcat, uint4* __restrict__ wobf,
    uint4* __restrict__ nbf,
    float* __restrict__ r_part, float* __restrict__ m_part,
    float* __restrict__ s_part)
{
    __shared__ __align__(16) float smem[4640];
    float* qs = smem;
    float (*red_r)[DCH] = (float (*)[DCH])(smem + 512);
    float* red_m = smem + 4608;
    float* red_s = smem + 4624;

    const int bid = blockIdx.x;
    const int b = bid >> 2, sl = bid & 3;
    const int t = threadIdx.x;

    // ---- weight conversion: 40 chunks per block ----
    if (t < 40) {
        int idx = bid * 40 + t;
        if (idx < 65536) {                         // Wcat chunk
            const int n = idx >> 6, k = (idx & 63) * 8;
            float v[8];
            *(float4*)(v)     = *(const float4*)(W_ih + (size_t)n * K2 + k);
            *(float4*)(v + 4) = *(const float4*)(W_ih + (size_t)n * K2 + k + 4);
            if (k < DCH) {
                float h[8];
                *(float4*)(h)     = *(const float4*)(W_hh + (size_t)n * DCH + k);
                *(float4*)(h + 4) = *(const float4*)(W_hh + (size_t)n * DCH + k + 4);
                #pragma unroll
                for (int i = 0; i < 8; ++i) v[i] += h[i];
            }
            uint4 u;
            u.x = pack2bf(v[0], v[1]); u.y = pack2bf(v[2], v[3]);
            u.z = pack2bf(v[4], v[5]); u.w = pack2bf(v[6], v[7]);
            wcat[idx] = u;
        } else {                                   // WoBf chunk
            const int i2 = idx - 65536;
            const int n = i2 >> 6, k = (i2 & 63) * 8;
            float v[8];
            *(float4*)(v)     = *(const float4*)(Wo + (size_t)n * K2 + k);
            *(float4*)(v + 4) = *(const float4*)(Wo + (size_t)n * K2 + k + 4);
            uint4 u;
            u.x = pack2bf(v[0], v[1]); u.y = pack2bf(v[2], v[3]);
            u.z = pack2bf(v[4], v[5]); u.w = pack2bf(v[6], v[7]);
            wobf[i2] = u;
        }
    }

    // ---- h from biases only (step-1 LSTM; c_old = 0) ----
    {
        float gv[4];
        #pragma unroll
        for (int q = 0; q < 4; ++q) gv[q] = b_ih[q * DCH + t] + b_hh[q * DCH + t];
        const float cn = sigf(gv[0]) * tanhf(gv[2]);
        const float hn = sigf(gv[3]) * tanhf(cn);
        qs[t] = hn;
    }
    __syncthreads();

    // ---- attention over slice [lo, hi): 16 clusters x 16 lanes ----
    const int w = t >> 6, l = t & 63;
    const int p = l & 15;
    const int g = w * 4 + (l >> 4);
    const int cnt = node_num[b];
    const int lo = sl * SLN;
    const int hi = min(lo + SLN, cnt);
    const float* nb = node + (size_t)b * NPG * DCH;
    uint4* nbf_b = nbf + (size_t)b * NPG * 32;

    float4 qv[4];
    #pragma unroll
    for (int j = 0; j < 2; ++j) {
        qv[j*2+0] = *(const float4*)(qs + j * 128 + p * 8);
        qv[j*2+1] = *(const float4*)(qs + j * 128 + p * 8 + 4);
    }

    auto ld = [&](int n, float4* x) {
        if (n < hi) {
            #pragma unroll
            for (int j = 0; j < 2; ++j) {
                x[j*2+0] = *(const float4*)(nb + (size_t)n * DCH + j * 128 + p * 8);
                x[j*2+1] = *(const float4*)(nb + (size_t)n * DCH + j * 128 + p * 8 + 4);
            }
        } else {
            x[0] = x[1] = x[2] = x[3] = make_float4(0.f, 0.f, 0.f, 0.f);
        }
    };
    auto st_bf = [&](int n, const float4* x) {
        if (n < hi) {
            #pragma unroll
            for (int j = 0; j < 2; ++j) {
                uint4 u;
                u.x = pack2bf(x[j*2+0].x, x[j*2+0].y);
                u.y = pack2bf(x[j*2+0].z, x[j*2+0].w);
                u.z = pack2bf(x[j*2+1].x, x[j*2+1].y);
                u.w = pack2bf(x[j*2+1].z, x[j*2+1].w);
                nbf_b[(size_t)n * 32 + j * 16 + p] = u;
            }
        }
    };

    float m = -INFINITY, ssum = 0.0f;
    float4 racc[4] = {};
    const int span = hi - lo;
    const int nit = (span > 0) ? ((span + 31) >> 5) : 0;

    float4 x0[4], x1[4], u0[4], u1[4];
    ld(lo + 2 * g, x0);      ld(lo + 2 * g + 1, x1);
    ld(lo + 32 + 2 * g, u0); ld(lo + 32 + 2 * g + 1, u1);

    for (int it = 0; it < nit; ++it) {
        const int n0 = lo + it * 32 + 2 * g;
        float4 y0[4], y1[4];
        ld(n0 + 64, y0); ld(n0 + 65, y1);
        st_bf(n0, x0); st_bf(n0 + 1, x1);

        float e0 = 0.f, e1 = 0.f;
        #pragma unroll
        for (int j = 0; j < 4; ++j) {
            e0 += x0[j].x * qv[j].x + x0[j].y * qv[j].y + x0[j].z * qv[j].z + x0[j].w * qv[j].w;
            e1 += x1[j].x * qv[j].x + x1[j].y * qv[j].y + x1[j].z * qv[j].z + x1[j].w * qv[j].w;
        }
        #pragma unroll
        for (int off = 1; off < 16; off <<= 1) {
            e0 += __shfl_xor(e0, off);
            e1 += __shfl_xor(e1, off);
        }
        if (n0     >= hi) e0 = -INFINITY;
        if (n0 + 1 >= hi) e1 = -INFINITY;
        const float mn = fmaxf(m, fmaxf(e0, e1));
        if (mn > -INFINITY) {
            const float sc = __expf(m - mn);
            const float w0 = __expf(e0 - mn);
            const float w1 = __expf(e1 - mn);
            ssum = ssum * sc + w0 + w1;
            #pragma unroll
            for (int j = 0; j < 4; ++j) {
                racc[j].x = racc[j].x * sc + w0 * x0[j].x + w1 * x1[j].x;
                racc[j].y = racc[j].y * sc + w0 * x0[j].y + w1 * x1[j].y;
                racc[j].z = racc[j].z * sc + w0 * x0[j].z + w1 * x1[j].z;
                racc[j].w = racc[j].w * sc + w0 * x0[j].w + w1 * x1[j].w;
            }
            m = mn;
        }
        #pragma unroll
        for (int j = 0; j < 4; ++j) {
            x0[j] = u0[j]; x1[j] = u1[j];
            u0[j] = y0[j]; u1[j] = y1[j];
        }
    }

    #pragma unroll
    for (int j = 0; j < 2; ++j) {
        *(float4*)(&red_r[g][j * 128 + p * 8])     = racc[j*2+0];
        *(float4*)(&red_r[g][j * 128 + p * 8 + 4]) = racc[j*2+1];
    }
    if (p == 0) { red_m[g] = m; red_s[g] = ssum; }
    __syncthreads();

    // cluster merge -> RAW partial (no normalize)
    float M = -INFINITY;
    #pragma unroll
    for (int g2 = 0; g2 < 16; ++g2) M = fmaxf(M, red_m[g2]);
    float stot = 0.0f, rtot = 0.0f;
    if (M > -INFINITY) {
        #pragma unroll
        for (int g2 = 0; g2 < 16; ++g2) {
            const float sc = __expf(red_m[g2] - M);
            stot += sc * red_s[g2];
            rtot += sc * red_r[g2][t];
        }
    }
    if (t == 0) { m_part[bid] = M; s_part[bid] = stot; }
    else if (t == 1) s_part[bid] = stot;   // redundant-safe (same value)
    r_part[(size_t)bid * DCH + t] = rtot;
}

// ---------------------------------------------------------------------------
// Pass-1 merge: combine 4 slice partials per graph, redo trivial step-1 LSTM,
// write cbuf + bf16 q_star.
// ---------------------------------------------------------------------------
__global__ __launch_bounds__(256) void attn1_merge_kernel(
    const float* __restrict__ r_part, const float* __restrict__ m_part,
    const float* __restrict__ s_part,
    const float* __restrict__ b_ih, const float* __restrict__ b_hh,
    float* __restrict__ cbuf, unsigned* __restrict__ hrbf)
{
    __shared__ __align__(16) float qsm[512];
    const int b = blockIdx.x, t = threadIdx.x;

    float gv[4];
    #pragma unroll
    for (int q = 0; q < 4; ++q) gv[q] = b_ih[q * DCH + t] + b_hh[q * DCH + t];
    const float cn = sigf(gv[0]) * tanhf(gv[2]);
    const float hn = sigf(gv[3]) * tanhf(cn);
    cbuf[b * DCH + t] = cn;
    qsm[t] = hn;

    float M = -INFINITY;
    #pragma unroll
    for (int ps = 0; ps < NSL; ++ps) M = fmaxf(M, m_part[b * NSL + ps]);
    float stot = 0.0f, rtot = 0.0f;
    #pragma unroll
    for (int ps = 0; ps < NSL; ++ps) {
        const float sc = __expf(m_part[b * NSL + ps] - M);
        stot += sc * s_part[b * NSL + ps];
        rtot += sc * r_part[(size_t)(b * NSL + ps) * DCH + t];
    }
    qsm[256 + t] = rtot / (stot + 1e-6f);
    __syncthreads();
    hrbf[b * 256 + t] = pack2bf(qsm[2 * t], qsm[2 * t + 1]);
}

// ---------------------------------------------------------------------------
// Passes 2-4: fused LSTM + attention (bf16 cache) (+ out-proj if LAST).
// Round-10 proven 256-thread form. 16 clusters x 16 lanes, depth-2 prefetch.
// ---------------------------------------------------------------------------
template<int LAST>
__global__ __launch_bounds__(256) void lstm_attn_kernel(
    const float* __restrict__ gpart,
    const float* __restrict__ b_ih, const float* __restrict__ b_hh,
    const uint4* __restrict__ nbf, const int* __restrict__ node_num,
    float* __restrict__ cbuf, unsigned* __restrict__ hrbf,
    const uint4* __restrict__ wobf, const float* __restrict__ bo,
    float* __restrict__ outp)
{
    __shared__ __align__(16) float smem[4640];
    float* qs = smem;
    float (*red_r)[DCH] = (float (*)[DCH])(smem + 512);
    float* red_m = smem + 4608;
    float* red_s = smem + 4624;

    const int b = blockIdx.x;
    const int t = threadIdx.x;

    // ---- LSTM cell (torch gate order i,f,g,o) ----
    float gv[4];
    #pragma unroll
    for (int q = 0; q < 4; ++q) {
        const int idx = q * DCH + t;
        float v = b_ih[idx] + b_hh[idx];
        #pragma unroll
        for (int z = 0; z < KSD; ++z)
            v += gpart[(size_t)z * BSZ * G4 + (size_t)b * G4 + idx];
        gv[q] = v;
    }
    const float c_old = cbuf[b * DCH + t];
    const float cn = sigf(gv[1]) * c_old + sigf(gv[0]) * tanhf(gv[2]);
    const float hn = sigf(gv[3]) * tanhf(cn);
    if (!LAST) cbuf[b * DCH + t] = cn;
    qs[t] = hn;
    __syncthreads();

    // ---- attention: bf16 cache, 16 clusters, depth-2 prefetch ----
    const int w = t >> 6, l = t & 63;
    const int p = l & 15;
    const int g = w * 4 + (l >> 4);
    const int cnt = node_num[b];
    const uint4* nbf_b = nbf + (size_t)b * NPG * 32;

    float4 qv[4];
    #pragma unroll
    for (int j = 0; j < 2; ++j) {
        qv[j*2+0] = *(const float4*)(qs + j * 128 + p * 8);
        qv[j*2+1] = *(const float4*)(qs + j * 128 + p * 8 + 4);
    }

    auto ld = [&](int n, float4* x) {
        if (n < cnt) {
            #pragma unroll
            for (int j = 0; j < 2; ++j) {
                const uint4 u = nbf_b[(size_t)n * 32 + j * 16 + p];
                x[j*2+0] = make_float4(lo_bf(u.x), hi_bf(u.x), lo_bf(u.y), hi_bf(u.y));
                x[j*2+1] = make_float4(lo_bf(u.z), hi_bf(u.z), lo_bf(u.w), hi_bf(u.w));
            }
        } else {
            x[0] = x[1] = x[2] = x[3] = make_float4(0.f, 0.f, 0.f, 0.f);
        }
    };

    float m = -INFINITY, ssum = 0.0f;
    float4 racc[4] = {};
    const int nit = (cnt + 31) >> 5;

    float4 x0[4], x1[4], u0[4], u1[4];
    ld(2 * g, x0);      ld(2 * g + 1, x1);
    ld(32 + 2 * g, u0); ld(32 + 2 * g + 1, u1);

    for (int it = 0; it < nit; ++it) {
        const int n0 = it * 32 + 2 * g;
        float4 y0[4], y1[4];
        ld(n0 + 64, y0); ld(n0 + 65, y1);

        float e0 = 0.f, e1 = 0.f;
        #pragma unroll
        for (int j = 0; j < 4; ++j) {
            e0 += x0[j].x * qv[j].x + x0[j].y * qv[j].y + x0[j].z * qv[j].z + x0[j].w * qv[j].w;
            e1 += x1[j].x * qv[j].x + x1[j].y * qv[j].y + x1[j].z * qv[j].z + x1[j].w * qv[j].w;
        }
        #pragma unroll
        for (int off = 1; off < 16; off <<= 1) {
            e0 += __shfl_xor(e0, off);
            e1 += __shfl_xor(e1, off);
        }
        if (n0     >= cnt) e0 = -INFINITY;
        if (n0 + 1 >= cnt) e1 = -INFINITY;
        const float mn = fmaxf(m, fmaxf(e0, e1));
        if (mn > -INFINITY) {
            const float sc = __expf(m - mn);
            const float w0 = __expf(e0 - mn);
            const float w1 = __expf(e1 - mn);
            ssum = ssum * sc + w0 + w1;
            #pragma unroll
            for (int j = 0; j < 4; ++j) {
                racc[j].x = racc[j].x * sc + w0 * x0[j].x + w1 * x1[j].x;
                racc[j].y = racc[j].y * sc + w0 * x0[j].y + w1 * x1[j].y;
                racc[j].z = racc[j].z * sc + w0 * x0[j].z + w1 * x1[j].z;
                racc[j].w = racc[j].w * sc + w0 * x0[j].w + w1 * x1[j].w;
            }
            m = mn;
        }
        #pragma unroll
        for (int j = 0; j < 4; ++j) {
            x0[j] = u0[j]; x1[j] = u1[j];
            u0[j] = y0[j]; u1[j] = y1[j];
        }
    }

    #pragma unroll
    for (int j = 0; j < 2; ++j) {
        *(float4*)(&red_r[g][j * 128 + p * 8])     = racc[j*2+0];
        *(float4*)(&red_r[g][j * 128 + p * 8 + 4]) = racc[j*2+1];
    }
    if (p == 0) { red_m[g] = m; red_s[g] = ssum; }
    __syncthreads();

    float M = -INFINITY;
    #pragma unroll
    for (int g2 = 0; g2 < 16; ++g2) M = fmaxf(M, red_m[g2]);
    float stot = 0.0f, rtot = 0.0f;
    #pragma unroll
    for (int g2 = 0; g2 < 16; ++g2) {
        const float sc = __expf(red_m[g2] - M);
        stot += sc * red_s[g2];
        rtot += sc * red_r[g2][t];
    }
    rtot = rtot / (stot + 1e-6f);

    qs[256 + t] = rtot;            // q_star = [h | r]
    __syncthreads();

    if (!LAST) {
        hrbf[b * 256 + t] = pack2bf(qs[2 * t], qs[2 * t + 1]);
        return;
    }

    // ---- fused output projection (Wo bf16) ----
    float4 qv2[8];
    #pragma unroll
    for (int j = 0; j < 4; ++j) {
        qv2[j*2+0] = *(const float4*)(qs + j * 128 + p * 8);
        qv2[j*2+1] = *(const float4*)(qs + j * 128 + p * 8 + 4);
    }
    float* out_sm = smem + 512;    // reuse red_r (post-barrier)

    #pragma unroll 2
    for (int v = 0; v < 8; ++v) {
        const int o0 = (2 * v) * 16 + g;
        const int o1 = o0 + 16;
        float e0 = 0.f, e1 = 0.f;
        #pragma unroll
        for (int j = 0; j < 4; ++j) {
            const uint4 ua = wobf[(size_t)o0 * 64 + j * 16 + p];
            const uint4 ub = wobf[(size_t)o1 * 64 + j * 16 + p];
            e0 += lo_bf(ua.x) * qv2[j*2].x + hi_bf(ua.x) * qv2[j*2].y
                + lo_bf(ua.y) * qv2[j*2].z + hi_bf(ua.y) * qv2[j*2].w
                + lo_bf(ua.z) * qv2[j*2+1].x + hi_bf(ua.z) * qv2[j*2+1].y
                + lo_bf(ua.w) * qv2[j*2+1].z + hi_bf(ua.w) * qv2[j*2+1].w;
            e1 += lo_bf(ub.x) * qv2[j*2].x + hi_bf(ub.x) * qv2[j*2].y
                + lo_bf(ub.y) * qv2[j*2].z + hi_bf(ub.y) * qv2[j*2].w
                + lo_bf(ub.z) * qv2[j*2+1].x + hi_bf(ub.z) * qv2[j*2+1].y
                + lo_bf(ub.w) * qv2[j*2+1].z + hi_bf(ub.w) * qv2[j*2+1].w;
        }
        #pragma unroll
        for (int off = 1; off < 16; off <<= 1) {
            e0 += __shfl_xor(e0, off);
            e1 += __shfl_xor(e1, off);
        }
        if (p == 0) {
            out_sm[o0] = e0 + bo[o0];
            out_sm[o1] = e1 + bo[o1];
        }
    }
    __syncthreads();
    outp[(size_t)b * DCH + t] = out_sm[t];
}

// ---------------------------------------------------------------------------
extern "C" void kernel_launch(void* const* d_in, const int* in_sizes, int n_in,
                              void* d_out, int out_size, void* d_ws, size_t ws_size,
                              hipStream_t stream)
{
    const float* node     = (const float*)d_in[0];
    const int*   node_num = (const int*)  d_in[1];
    const float* W_ih     = (const float*)d_in[2];
    const float* W_hh     = (const float*)d_in[3];
    const float* b_ih     = (const float*)d_in[4];
    const float* b_hh     = (const float*)d_in[5];
    const float* Wo       = (const float*)d_in[6];
    const float* bo       = (const float*)d_in[7];
    float* out = (float*)d_out;

    float* ws      = (float*)d_ws;
    float* cbuf    = ws;                                   // 512*256 f32
    unsigned* hrbf = (unsigned*)(cbuf + BSZ * DCH);        // 512*256 u32
    float* gpart   = (float*)(hrbf + BSZ * 256);           // 4*512*1024 f32 (8 MB)
    uint4* wcat    = (uint4*)(gpart + (size_t)KSD * BSZ * G4);   // 1 MB
    uint4* wobf    = wcat + 1024 * 64;                     // 256 KB
    float* m_part  = (float*)(wobf + 256 * 64);            // 2048 f32
    float* s_part  = m_part + BSZ * NSL;                   // 2048 f32
    float* r_part  = s_part + BSZ * NSL;                   // 2048*256 f32 (2 MB)
    uint4* nbf     = (uint4*)(r_part + (size_t)BSZ * NSL * DCH); // 52.4 MB

    // pass 1: split across 4 blocks/graph for occupancy; builds bf16 caches
    attn1_part_kernel<<<BSZ * NSL, 256, 0, stream>>>(
        node, node_num, b_ih, b_hh, W_ih, W_hh, Wo,
        wcat, wobf, nbf, r_part, m_part, s_part);
    attn1_merge_kernel<<<BSZ, 256, 0, stream>>>(
        r_part, m_part, s_part, b_ih, b_hh, cbuf, hrbf);

    for (int s = 1; s < 4; ++s) {
        gemm_gates_mfma<<<dim3(8, 8, KSD), 256, 0, stream>>>(
            (const unsigned short*)hrbf, (const unsigned short*)wcat, gpart, K2 / KSD);
        if (s < 3) {
            lstm_attn_kernel<0><<<BSZ, 256, 0, stream>>>(
                gpart, b_ih, b_hh, nbf, node_num, cbuf, hrbf, wobf, bo, out);
        } else {
            lstm_attn_kernel<1><<<BSZ, 256, 0, stream>>>(
                gpart, b_ih, b_hh, nbf, node_num, cbuf, hrbf, wobf, bo, out);
        }
    }
}